// Round 5
// baseline (3693.410 us; speedup 1.0000x reference)
//
#include <hip/hip_runtime.h>
#include <hip/hip_bf16.h>

#define SEQ  2048
#define EDIM 300
#define HDIM 150
#define FH   600   // 4*H
#define DDIM 300   // 2*H
#define DE   600   // D + E

__device__ __forceinline__ float frcp_(float x) { return __builtin_amdgcn_rcpf(x); }
__device__ __forceinline__ float sigm_(float x) { return frcp_(1.f + __expf(-x)); }
__device__ __forceinline__ float tanh_(float x) { return 1.f - 2.f * frcp_(1.f + __expf(2.f * x)); }

__device__ __forceinline__ float wave_red(float v) {
#pragma unroll
    for (int off = 32; off; off >>= 1) v += __shfl_down(v, off, 64);
    return v;
}

__device__ __forceinline__ float rl_(float v, int l) {
    return __uint_as_float((unsigned)__builtin_amdgcn_readlane(__float_as_uint(v), l));
}

// ---------------------------------------------------------------------------
// xp = gather(emb, sentence) @ W{f,b} + b{f,b}   -> [SEQ,600] per direction
// ---------------------------------------------------------------------------
__global__ __launch_bounds__(256) void k_xp(
    const int* __restrict__ sent, const float* __restrict__ emb,
    const float* __restrict__ Wf, const float* __restrict__ bfv,
    const float* __restrict__ Wb, const float* __restrict__ bbv,
    float* __restrict__ xpf, float* __restrict__ xpb)
{
    __shared__ float xs[16][EDIM];
    const int tid = threadIdx.x;
    const int t0  = blockIdx.x * 16;

    for (int i = tid; i < 16 * EDIM; i += 256) {
        int r = i / EDIM, e = i - r * EDIM;
        int row = sent[t0 + r];
        xs[r][e] = emb[(size_t)row * EDIM + e];
    }
    __syncthreads();

    float acc[5][16];
#pragma unroll
    for (int c = 0; c < 5; c++)
#pragma unroll
        for (int r = 0; r < 16; r++) acc[c][r] = 0.f;

    const float* wp[5];
    bool val[5];
#pragma unroll
    for (int c = 0; c < 5; c++) {
        int j = tid + 256 * c;
        val[c] = (j < 1200);
        wp[c] = (j < 600) ? (Wf + j) : (Wb + (j < 1200 ? j - 600 : 0));
    }

    for (int e = 0; e < EDIM; e++) {
        float xr[16];
#pragma unroll
        for (int r = 0; r < 16; r++) xr[r] = xs[r][e];
#pragma unroll
        for (int c = 0; c < 5; c++) {
            if (val[c]) {
                float w = wp[c][(size_t)e * FH];
#pragma unroll
                for (int r = 0; r < 16; r++) acc[c][r] += xr[r] * w;
            }
        }
    }

#pragma unroll
    for (int c = 0; c < 5; c++) {
        int j = tid + 256 * c;
        if (j < 1200) {
            bool isF = (j < 600);
            int jj = isF ? j : j - 600;
            float bias = isF ? bfv[jj] : bbv[jj];
            float* dst = isF ? xpf : xpb;
#pragma unroll
            for (int r = 0; r < 16; r++)
                dst[(size_t)(t0 + r) * FH + jj] = acc[c][r] + bias;
        }
    }
}

// ---------------------------------------------------------------------------
// Serial LSTM recurrence. Block 0 = forward, block 1 = backward.
//
// Round-4/5 structure (kills the AGPR-move bloat seen in r1/r3 and the
// sparse-lane gate reduce):
//   1024 threads = 16 waves = 4 waves/SIMD (launch_bounds(1024,4) -> 128 VGPR
//   cap). Wave wv = (kg = wv&7, cg = wv>>3):
//     kg owns k-slice [19kg, 19kg+19)  (rows >=150 zero-padded)
//     cg owns column half [300cg, 300cg+300); lane covers 5 cols.
//   U per thread = 19x5 = 95 fp32 -> fits ARCHITECTED VGPRs, no accvgpr moves.
//
//   Per step, three phases:
//     A: each wave computes its k-slice partial for its 300 cols
//        (19 wave-local readlanes + 95 FMA), stores zpart[kg][col].
//     B: threads 0..599 own one z-column each: sum 8 partials with dense
//        full-wave conflict-free ds_read_b32, add own prefetched xp value,
//        apply sigm/tanh, store act[col].
//     C: lanes 0..18 of every wave rebuild h/c from 4 act-reads (wave-local,
//        so NO barrier between C and the next A's readlanes).
//   Two raw lgkm-only barriers per step (vmcnt stays in flight: xp prefetch
//   and hs stores cross the barriers). zpart/act single-buffered: A'(next
//   step) only runs after bar2, by which point all B-reads of zpart are done;
//   B' only runs after bar1', by which point all C-reads of act are done.
// ---------------------------------------------------------------------------
__global__ __launch_bounds__(1024, 4) void k_lstm(
    const float* __restrict__ Uf, const float* __restrict__ Ub,
    const float* __restrict__ xpf, const float* __restrict__ xpb,
    float* __restrict__ hs)
{
    const int dir = blockIdx.x;
    const float* __restrict__ U  = dir ? Ub : Uf;
    const float* __restrict__ xp = dir ? xpb : xpf;

    __shared__ float zpart[8][FH];   // [kg][col] = 19.2 KiB
    __shared__ float act[FH];        // activated gates (i,f,g,o) = 2.4 KiB

    const int tid  = threadIdx.x;    // 0..1023
    const int lane = tid & 63;
    const int wv   = tid >> 6;       // 0..15
    const int kg   = wv & 7;         // k-group (slice of 19)
    const int cg   = wv >> 3;        // column-half group
    const int kw0  = kg * 19;

    // 5 columns per lane within the half (5th valid iff lane<44)
    const bool has5 = (lane < 44);
    int col[5];
#pragma unroll
    for (int g = 0; g < 5; g++) {
        int c = 300 * cg + 64 * g + lane;
        col[g] = (g == 4 && !has5) ? (300 * cg + 299) : c;
    }

    // U k-slice for my 5 columns: 95 fp32, true VGPRs
    float Ur[5][19];
#pragma unroll
    for (int kk = 0; kk < 19; kk++) {
        const int k   = kw0 + kk;
        const bool kv = (k < HDIM);
        const float* row = U + (size_t)(kv ? k : 0) * FH;
        const float m = kv ? 1.f : 0.f;
#pragma unroll
        for (int g = 0; g < 5; g++)
            Ur[g][kk] = m * row[col[g]];
    }

    // C-role: lane l of wave (kg,*) owns h[kw0+l], c[kw0+l]
    const int j  = kw0 + lane;
    const bool gv = (lane < 19) && (j < HDIM);
    float hreg = 0.f, creg = 0.f;

    // B-role: thread tid<600 owns z-column tid (gate gsel, index jb)
    const bool bv   = (tid < FH);
    const int  gsel = tid / 150;               // 0:i 1:f 2:g 3:o (thread-const)
    float xq = 0.f;
    if (bv) xq = xp[(size_t)(dir ? (SEQ - 1) : 0) * FH + tid];

    for (int step = 0; step < SEQ; step++) {
        const int t = dir ? (SEQ - 1 - step) : step;

        // ---- A: partial_kg[col] = sum_{k in slice} h[k] * U[k][col] ----
        float s0 = 0.f, s1 = 0.f, s2 = 0.f, s3 = 0.f, s4 = 0.f;
#pragma unroll
        for (int kk = 0; kk < 19; kk++) {
            const float hk = rl_(hreg, kk);    // wave-local broadcast
            s0 = fmaf(hk, Ur[0][kk], s0);
            s1 = fmaf(hk, Ur[1][kk], s1);
            s2 = fmaf(hk, Ur[2][kk], s2);
            s3 = fmaf(hk, Ur[3][kk], s3);
            s4 = fmaf(hk, Ur[4][kk], s4);
        }
        zpart[kg][col[0]] = s0;
        zpart[kg][col[1]] = s1;
        zpart[kg][col[2]] = s2;
        zpart[kg][col[3]] = s3;
        if (has5) zpart[kg][col[4]] = s4;

        asm volatile("s_waitcnt lgkmcnt(0)" ::: "memory");
        __builtin_amdgcn_sched_barrier(0);
        __builtin_amdgcn_s_barrier();
        __builtin_amdgcn_sched_barrier(0);

        // ---- B: dense z-reduce + activation (threads 0..599) ----
        if (bv) {
            float z = xq;
#pragma unroll
            for (int k8 = 0; k8 < 8; k8++)
                z += zpart[k8][tid];           // full-wave, conflict-free

            // prefetch next step's xp while the activation runs
            if (step + 1 < SEQ) {
                const int tn = dir ? (SEQ - 2 - step) : (step + 1);
                xq = xp[(size_t)tn * FH + tid];
            }

            act[tid] = (gsel == 2) ? tanh_(z) : sigm_(z);
        }

        asm volatile("s_waitcnt lgkmcnt(0)" ::: "memory");
        __builtin_amdgcn_sched_barrier(0);
        __builtin_amdgcn_s_barrier();
        __builtin_amdgcn_sched_barrier(0);

        // ---- C: rebuild h/c (wave-local; no barrier before next A) ----
        if (gv) {
            const float ig = act[j];
            const float fg = act[HDIM + j];
            const float gg = act[2 * HDIM + j];
            const float og = act[3 * HDIM + j];
            creg = fg * creg + ig * gg;
            hreg = og * tanh_(creg);
            if (cg == 0)
                hs[(size_t)t * DDIM + dir * HDIM + j] = hreg;  // fire-and-forget
        }
    }
}

// ---------------------------------------------------------------------------
// out_e = hs @ W_pe + b_pe ; out_s = hs @ W_ps + b_ps
// ---------------------------------------------------------------------------
__global__ __launch_bounds__(256) void k_out(
    const float* __restrict__ hs,
    const float* __restrict__ Wpe, const float* __restrict__ bpe,
    const float* __restrict__ Wps, const float* __restrict__ bps,
    float* __restrict__ oe, float* __restrict__ os)
{
    __shared__ float xs[16 * DDIM];
    const int tid = threadIdx.x;
    const int t0  = blockIdx.x * 16;

    for (int i = tid; i < 16 * DDIM; i += 256) xs[i] = hs[(size_t)t0 * DDIM + i];
    __syncthreads();

    float acc[3][16];
#pragma unroll
    for (int c = 0; c < 3; c++)
#pragma unroll
        for (int r = 0; r < 16; r++) acc[c][r] = 0.f;

    const float* wp[3];
    bool val[3];
#pragma unroll
    for (int c = 0; c < 3; c++) {
        int j = tid + 256 * c;
        val[c] = (j < 600);
        wp[c] = (j < 300) ? (Wpe + j) : (Wps + (j < 600 ? j - 300 : 0));
    }

    for (int e = 0; e < DDIM; e++) {
        float xr[16];
#pragma unroll
        for (int r = 0; r < 16; r++) xr[r] = xs[r * DDIM + e];
#pragma unroll
        for (int c = 0; c < 3; c++) {
            if (val[c]) {
                float w = wp[c][(size_t)e * DDIM];
#pragma unroll
                for (int r = 0; r < 16; r++) acc[c][r] += xr[r] * w;
            }
        }
    }

#pragma unroll
    for (int c = 0; c < 3; c++) {
        int j = tid + 256 * c;
        if (j < 600) {
            bool isE = (j < 300);
            int jj = isE ? j : j - 300;
            float bias = isE ? bpe[jj] : bps[jj];
            float* dst = isE ? oe : os;
#pragma unroll
            for (int r = 0; r < 16; r++)
                dst[(size_t)(t0 + r) * DDIM + jj] = acc[c][r] + bias;
        }
    }
}

// ---------------------------------------------------------------------------
// Primary + secondary attention, accumulate H_HAT / H_BAR (8 sentences/block)
// ---------------------------------------------------------------------------
__global__ __launch_bounds__(256) void k_attn(
    const int* __restrict__ sent, const int* __restrict__ syn,
    const float* __restrict__ emb,
    const float* __restrict__ hs, const float* __restrict__ oeA, const float* __restrict__ osA,
    const float* __restrict__ w_se, const float* __restrict__ b_se,
    const float* __restrict__ w_ss, const float* __restrict__ b_ss,
    float* __restrict__ accHat, float* __restrict__ accBar)
{
    __shared__ float Loe[DDIM], Los[DDIM], Lh[DDIM];
    __shared__ float Lsyn[4][EDIM];
    __shared__ float Lme[EDIM], Lms[EDIM];
    __shared__ float Lred[4][8];
    __shared__ float Latt[8];
    __shared__ float Lco[2];

    const int tid = threadIdx.x;
    const int wv = tid >> 6, lane = tid & 63;
    float aH[3] = {0.f, 0.f, 0.f}, aB[3] = {0.f, 0.f, 0.f};

    for (int i8 = 0; i8 < 8; i8++) {
        const int s = blockIdx.x * 8 + i8;
        for (int i = tid; i < DDIM; i += 256) {
            Loe[i] = oeA[(size_t)s * DDIM + i];
            Los[i] = osA[(size_t)s * DDIM + i];
            Lh[i]  = hs [(size_t)s * DDIM + i];
        }
        const int sid = sent[s];
        for (int i = tid; i < 4 * EDIM; i += 256) {
            int k4 = i / EDIM, e = i - k4 * EDIM;
            int row = syn[sid * 4 + k4];
            Lsyn[k4][e] = emb[(size_t)row * EDIM + e];
        }
        __syncthreads();

        float p[8];
#pragma unroll
        for (int q = 0; q < 8; q++) p[q] = 0.f;
        for (int d = tid; d < EDIM; d += 256) {
            float voe = Loe[d], vos = Los[d];
#pragma unroll
            for (int k4 = 0; k4 < 4; k4++) {
                float sv = Lsyn[k4][d];
                p[k4]     += voe * sv;
                p[4 + k4] += vos * sv;
            }
        }
#pragma unroll
        for (int q = 0; q < 8; q++) {
            float r = wave_red(p[q]);
            if (lane == 0) Lred[wv][q] = r;
        }
        __syncthreads();
        if (tid < 8)
            Latt[tid] = __expf(Lred[0][tid] + Lred[1][tid] + Lred[2][tid] + Lred[3][tid]);
        __syncthreads();

        for (int d = tid; d < EDIM; d += 256) {
            float me = 0.f, ms = 0.f;
#pragma unroll
            for (int k4 = 0; k4 < 4; k4++) {
                float sv = Lsyn[k4][d];
                me += Latt[k4] * sv;
                ms += Latt[4 + k4] * sv;
            }
            Lme[d] = me; Lms[d] = ms;
        }
        __syncthreads();

        float pe = 0.f, ps = 0.f;
        for (int d = tid; d < DE; d += 256) {
            float ve = (d < DDIM) ? Lh[d] : Lme[d - DDIM];
            float vs = (d < DDIM) ? Lh[d] : Lms[d - DDIM];
            pe += ve * w_se[d];
            ps += vs * w_ss[d];
        }
        pe = wave_red(pe); ps = wave_red(ps);
        if (lane == 0) { Lred[wv][0] = pe; Lred[wv][1] = ps; }
        __syncthreads();
        if (tid == 0) {
            float de_ = Lred[0][0] + Lred[1][0] + Lred[2][0] + Lred[3][0];
            float ds_ = Lred[0][1] + Lred[1][1] + Lred[2][1] + Lred[3][1];
            Lco[0] = __expf(tanh_(de_ + b_se[0]));
            Lco[1] = __expf(tanh_(ds_ + b_ss[0]));
        }
        __syncthreads();
        float ce = Lco[0], cs = Lco[1];
#pragma unroll
        for (int cc = 0; cc < 3; cc++) {
            int d = tid + 256 * cc;
            if (d < DE) {
                float ve = (d < DDIM) ? Lh[d] : Lme[d - DDIM];
                float vs = (d < DDIM) ? Lh[d] : Lms[d - DDIM];
                aB[cc] += ce * ve;
                aH[cc] += cs * vs;
            }
        }
        __syncthreads();
    }

#pragma unroll
    for (int cc = 0; cc < 3; cc++) {
        int d = tid + 256 * cc;
        if (d < DE) {
            atomicAdd(&accHat[d], aH[cc]);
            atomicAdd(&accBar[d], aB[cc]);
        }
    }
}

// ---------------------------------------------------------------------------
// Final logits: emotion = H_BAR @ W_eo + b_eo ; sentiment = H_HAT @ W_so + b_so
// ---------------------------------------------------------------------------
__global__ __launch_bounds__(64) void k_final(
    const float* __restrict__ accHat, const float* __restrict__ accBar,
    const float* __restrict__ W_eo, const float* __restrict__ b_eo,
    const float* __restrict__ W_so, const float* __restrict__ b_so,
    float* __restrict__ out)
{
    const int lane = threadIdx.x;
#pragma unroll
    for (int jq = 0; jq < 8; jq++) {
        float pp = 0.f;
        for (int d = lane; d < DE; d += 64) pp += accBar[d] * W_eo[d * 8 + jq];
        pp = wave_red(pp);
        if (lane == 0) out[jq] = pp + b_eo[jq];
    }
    float pp = 0.f;
    for (int d = lane; d < DE; d += 64) pp += accHat[d] * W_so[d];
    pp = wave_red(pp);
    if (lane == 0) out[8] = pp + b_so[0];
}

extern "C" void kernel_launch(void* const* d_in, const int* in_sizes, int n_in,
                              void* d_out, int out_size, void* d_ws, size_t ws_size,
                              hipStream_t stream)
{
    const int*   sent = (const int*)  d_in[0];
    const float* emb  = (const float*)d_in[1];
    const int*   syn  = (const int*)  d_in[2];
    const float* Wf   = (const float*)d_in[3];
    const float* Uf   = (const float*)d_in[4];
    const float* bfv  = (const float*)d_in[5];
    const float* Wb   = (const float*)d_in[6];
    const float* Ub   = (const float*)d_in[7];
    const float* bbv  = (const float*)d_in[8];
    const float* Wpe  = (const float*)d_in[9];
    const float* bpe  = (const float*)d_in[10];
    const float* Wps  = (const float*)d_in[11];
    const float* bps  = (const float*)d_in[12];
    const float* wse  = (const float*)d_in[13];
    const float* bse  = (const float*)d_in[14];
    const float* wss  = (const float*)d_in[15];
    const float* bss  = (const float*)d_in[16];
    const float* Weo  = (const float*)d_in[17];
    const float* beo  = (const float*)d_in[18];
    const float* Wso  = (const float*)d_in[19];
    const float* bso  = (const float*)d_in[20];

    float* ws  = (float*)d_ws;
    float* xpf = ws;
    float* xpb = xpf + (size_t)SEQ * FH;
    float* hsA = xpb + (size_t)SEQ * FH;
    float* oeA = hsA + (size_t)SEQ * DDIM;
    float* osA = oeA + (size_t)SEQ * DDIM;
    float* accHat = osA + (size_t)SEQ * DDIM;
    float* accBar = accHat + DE;

    hipMemsetAsync(accHat, 0, 2 * DE * sizeof(float), stream);

    k_xp  <<<SEQ / 16, 256, 0, stream>>>(sent, emb, Wf, bfv, Wb, bbv, xpf, xpb);
    k_lstm<<<2,       1024, 0, stream>>>(Uf, Ub, xpf, xpb, hsA);
    k_out <<<SEQ / 16, 256, 0, stream>>>(hsA, Wpe, bpe, Wps, bps, oeA, osA);
    k_attn<<<SEQ / 8,  256, 0, stream>>>(sent, syn, emb, hsA, oeA, osA,
                                         wse, bse, wss, bss, accHat, accBar);
    k_final<<<1,        64, 0, stream>>>(accHat, accBar, Weo, beo, Wso, bso,
                                         (float*)d_out);
}